// Round 1
// baseline (316.568 us; speedup 1.0000x reference)
//
#include <hip/hip_runtime.h>

// Problem constants: B=1, S=4096, D=768, H=12, Dh=64
#define S_LEN 4096
#define D_MODEL 768
#define N_HEADS 12
#define D_HEAD 64

typedef short bf16x8 __attribute__((ext_vector_type(8)));   // MFMA A/B operand (8 bf16, 4 VGPRs)
typedef float f32x4 __attribute__((ext_vector_type(4)));    // MFMA C/D operand
typedef float f32x4v __attribute__((ext_vector_type(4)));
typedef unsigned short u16;
typedef unsigned short u16x8 __attribute__((ext_vector_type(8)));

// fp32 -> bf16 round-to-nearest-even
__device__ __forceinline__ u16 f2bf(float f) {
  unsigned u = __float_as_uint(f);
  u += 0x7FFFu + ((u >> 16) & 1u);
  return (u16)(u >> 16);
}

// async global->LDS, 16B per lane; LDS dest is wave-uniform base + lane*16 (m104 caveat):
// all LDS layouts staged this way are contiguous 1KB per wave-issue.
__device__ __forceinline__ void gl_lds16(const void* g, void* l) {
  __builtin_amdgcn_global_load_lds(
      (const __attribute__((address_space(1))) void*)g,
      (__attribute__((address_space(3))) void*)l, 16, 0, 0);
}

// ---------------------------------------------------------------- conversion
struct CvtArgs {
  const float* s[4];
  u16* d[4];
};

__global__ __launch_bounds__(256) void cvt8_kernel(CvtArgs a, long n) {
  const float* s = a.s[blockIdx.z];
  u16* d = a.d[blockIdx.z];
  long i = ((long)blockIdx.x * 256 + threadIdx.x) * 8;
  if (i >= n) return;
  f32x4v v0 = *(const f32x4v*)(s + i);
  f32x4v v1 = *(const f32x4v*)(s + i + 4);
  u16x8 o;
#pragma unroll
  for (int j = 0; j < 4; ++j) { o[j] = f2bf(v0[j]); o[j + 4] = f2bf(v1[j]); }
  *(u16x8*)(d + i) = o;
}

// ---------------------------------------------------------------- projection GEMM
// Out[m][n] = (sum_k A[m][k] * W[n][k] + bias[n]) * scale
// A: M x 768 bf16 row-major; W: N x 768 bf16 row-major (i.e. X @ W^T).
// mode 0: bf16 store row-major (ld 768); mode 1: bf16 store transposed (Out[n][m], ld 4096);
// mode 2: fp32 store row-major.
struct ProjArgs {
  const u16* A[3];
  const u16* W[3];
  const float* bias[3];
  void* out[3];
  float scale[3];
  int mode[3];
};

__global__ __launch_bounds__(256, 2) void proj_kernel(ProjArgs args) {
  const int z = blockIdx.z;
  const u16* __restrict__ A = args.A[z];
  const u16* __restrict__ W = args.W[z];
  const float* __restrict__ bias = args.bias[z];
  const float scale = args.scale[z];
  const int mode = args.mode[z];

  __shared__ u16 Al[128 * 32];  // 128 rows x 32 k, stride 32 (2-way bank alias: free)
  __shared__ u16 Bl[128 * 32];

  const int tid = threadIdx.x;
  const int w = tid >> 6, l = tid & 63;
  const int l15 = l & 15, quad = l >> 4;
  const int m0 = blockIdx.x * 128;
  const int n0 = blockIdx.y * 128;
  const int wm = (w & 1) * 64, wn = (w >> 1) * 64;
  const int crow = l >> 2, ccol = (l & 3) * 8;  // within a 1KB wave-issue: 16 rows x 32 elems

  f32x4 acc[4][4] = {};

  for (int kt = 0; kt < 24; ++kt) {
    const int k0 = kt * 32;
#pragma unroll
    for (int i = 0; i < 2; ++i) {
      const int sub = w * 2 + i;           // 8 x 1KB chunks per tile, distinct per (w,i)
      const int row = sub * 16 + crow;
      gl_lds16(&A[(size_t)(m0 + row) * D_MODEL + k0 + ccol], &Al[sub * 512 + l * 8]);
      gl_lds16(&W[(size_t)(n0 + row) * D_MODEL + k0 + ccol], &Bl[sub * 512 + l * 8]);
    }
    __syncthreads();
    bf16x8 af[4], bfr[4];
#pragma unroll
    for (int mf = 0; mf < 4; ++mf)
      af[mf] = *(const bf16x8*)&Al[(wm + mf * 16 + l15) * 32 + quad * 8];
#pragma unroll
    for (int nf = 0; nf < 4; ++nf)
      bfr[nf] = *(const bf16x8*)&Bl[(wn + nf * 16 + l15) * 32 + quad * 8];
#pragma unroll
    for (int mf = 0; mf < 4; ++mf)
#pragma unroll
      for (int nf = 0; nf < 4; ++nf)
        acc[mf][nf] = __builtin_amdgcn_mfma_f32_16x16x32_bf16(af[mf], bfr[nf], acc[mf][nf], 0, 0, 0);
    __syncthreads();
  }

  // C/D layout: col = lane&15, row = quad*4 + reg (m89/m91 verified)
#pragma unroll
  for (int nf = 0; nf < 4; ++nf) {
    const int col = n0 + wn + nf * 16 + l15;
    const float bv = bias[col];
#pragma unroll
    for (int mf = 0; mf < 4; ++mf) {
#pragma unroll
      for (int r = 0; r < 4; ++r) {
        const int row = m0 + wm + mf * 16 + quad * 4 + r;
        const float v = (acc[mf][nf][r] + bv) * scale;
        if (mode == 0)      ((u16*)args.out[z])[(size_t)row * D_MODEL + col] = f2bf(v);
        else if (mode == 1) ((u16*)args.out[z])[(size_t)col * S_LEN + row] = f2bf(v);
        else                ((float*)args.out[z])[(size_t)row * D_MODEL + col] = v;
      }
    }
  }
}

// ---------------------------------------------------------------- flash attention
// Q already scaled by (1/8)*log2(e) -> softmax in exp2 domain.
// Grid: (S/64, H). Block: 256 thr = 4 waves; wave w owns q rows [blk*64 + w*16, +16).
// K-tiles of 128; K_lds and Vt_lds in [kf][row][32] chunks so b128 reads stay 2-way.
__global__ __launch_bounds__(256, 2) void flash_kernel(
    const u16* __restrict__ Qb, const u16* __restrict__ Kb,
    const u16* __restrict__ Vt, const int* __restrict__ mask,
    u16* __restrict__ Ctx) {
  __shared__ u16 Kl[2][128 * 32];   // [kf over Dh][n(key idx)*32 + c] : 16KB
  __shared__ u16 Vl[4][64 * 32];    // [kf over BK][n(Dh)*32 + c]      : 16KB
  __shared__ u16 Pl[4][4 * 16 * 40];  // per-wave [kf(4)][row(16)][40]  : 20KB (pad 40 breaks bank hits)

  const int tid = threadIdx.x;
  const int w = tid >> 6, l = tid & 63;
  const int l15 = l & 15, quad = l >> 4;
  const int h = blockIdx.y;
  const int q0 = blockIdx.x * 64 + w * 16;
  const int crow = l >> 2, ccol = (l & 3) * 8;

  // Q fragments (A-operand layout: A[m=lane&15][k=quad*8+j]), held for whole kernel
  bf16x8 aq[2];
#pragma unroll
  for (int kf = 0; kf < 2; ++kf)
    aq[kf] = *(const bf16x8*)&Qb[(size_t)(q0 + l15) * D_MODEL + h * D_HEAD + kf * 32 + quad * 8];

  f32x4 oacc[4] = {};
  float mrun[4], lrun[4];
#pragma unroll
  for (int r = 0; r < 4; ++r) { mrun[r] = -1e30f; lrun[r] = 0.f; }

  for (int t = 0; t < 32; ++t) {
    const int s0 = t * 128;
    // stage K tile (16 x 1KB) + V^T tile (16 x 1KB); 8 wave-issues each wave
#pragma unroll
    for (int i = 0; i < 8; ++i) {
      const int issue = w * 8 + i;
      if (issue < 16) {
        const int kf = issue >> 3, sub = issue & 7;
        const int n = sub * 16 + crow;
        gl_lds16(&Kb[(size_t)(s0 + n) * D_MODEL + h * D_HEAD + kf * 32 + ccol],
                 &Kl[kf][sub * 512 + l * 8]);
      } else {
        const int vi = issue - 16;
        const int kf = vi >> 2, sub = vi & 3;
        const int n = sub * 16 + crow;
        gl_lds16(&Vt[(size_t)(h * D_HEAD + n) * S_LEN + s0 + kf * 32 + ccol],
                 &Vl[kf][sub * 512 + l * 8]);
      }
    }
    __syncthreads();

    // scores: S[m][n] = sum_d Q[m][d] K[n][d]; B-operand B[d][n]=K[n][d] -> row-major K reads
    f32x4 sacc[8] = {};
#pragma unroll
    for (int kf = 0; kf < 2; ++kf)
#pragma unroll
      for (int nf = 0; nf < 8; ++nf) {
        bf16x8 bk = *(const bf16x8*)&Kl[kf][(nf * 16 + l15) * 32 + quad * 8];
        sacc[nf] = __builtin_amdgcn_mfma_f32_16x16x32_bf16(aq[kf], bk, sacc[nf], 0, 0, 0);
      }

    // key-position mask (columns)
#pragma unroll
    for (int nf = 0; nf < 8; ++nf) {
      if (mask[s0 + nf * 16 + l15] == 0) {
#pragma unroll
        for (int r = 0; r < 4; ++r) sacc[nf][r] = -1e30f;
      }
    }

    // online softmax (exp2 domain); row r lives in 16-lane group sharing quad
    float mnew[4], alpha[4], rsum[4];
#pragma unroll
    for (int r = 0; r < 4; ++r) {
      float mx = sacc[0][r];
#pragma unroll
      for (int nf = 1; nf < 8; ++nf) mx = fmaxf(mx, sacc[nf][r]);
#pragma unroll
      for (int ofs = 1; ofs < 16; ofs <<= 1) mx = fmaxf(mx, __shfl_xor(mx, ofs, 64));
      mnew[r] = fmaxf(mrun[r], mx);
      alpha[r] = exp2f(mrun[r] - mnew[r]);
      mrun[r] = mnew[r];
      rsum[r] = 0.f;
    }
#pragma unroll
    for (int nf = 0; nf < 8; ++nf)
#pragma unroll
      for (int r = 0; r < 4; ++r) {
        const float p = exp2f(sacc[nf][r] - mnew[r]);
        sacc[nf][r] = p;
        rsum[r] += p;
      }
#pragma unroll
    for (int r = 0; r < 4; ++r) {
#pragma unroll
      for (int ofs = 1; ofs < 16; ofs <<= 1) rsum[r] += __shfl_xor(rsum[r], ofs, 64);
      lrun[r] = lrun[r] * alpha[r] + rsum[r];
    }
#pragma unroll
    for (int nfo = 0; nfo < 4; ++nfo)
#pragma unroll
      for (int r = 0; r < 4; ++r) oacc[nfo][r] *= alpha[r];

    // P: C-layout -> LDS -> A-layout (m120-verified transform)
#pragma unroll
    for (int nf = 0; nf < 8; ++nf) {
      const int kf = nf >> 1;
      const int cb = (nf & 1) * 16 + l15;
#pragma unroll
      for (int r = 0; r < 4; ++r)
        Pl[w][kf * 640 + (quad * 4 + r) * 40 + cb] = f2bf(sacc[nf][r]);
    }
    bf16x8 ap[4];
#pragma unroll
    for (int kf = 0; kf < 4; ++kf)
      ap[kf] = *(const bf16x8*)&Pl[w][kf * 640 + l15 * 40 + quad * 8];

    // O += P @ V ; B[k][n] = V[s0+k][h*64+n] = Vt tile, k-contiguous in Vl chunks
#pragma unroll
    for (int nfo = 0; nfo < 4; ++nfo)
#pragma unroll
      for (int kf = 0; kf < 4; ++kf) {
        bf16x8 bv = *(const bf16x8*)&Vl[kf][(nfo * 16 + l15) * 32 + quad * 8];
        oacc[nfo] = __builtin_amdgcn_mfma_f32_16x16x32_bf16(ap[kf], bv, oacc[nfo], 0, 0, 0);
      }
    __syncthreads();
  }

  // epilogue: ctx = O / l
#pragma unroll
  for (int r = 0; r < 4; ++r) {
    const float inv = 1.0f / lrun[r];
    const int row = q0 + quad * 4 + r;
#pragma unroll
    for (int nfo = 0; nfo < 4; ++nfo)
      Ctx[(size_t)row * D_MODEL + h * D_HEAD + nfo * 16 + l15] = f2bf(oacc[nfo][r] * inv);
  }
}

// ---------------------------------------------------------------- launch
extern "C" void kernel_launch(void* const* d_in, const int* in_sizes, int n_in,
                              void* d_out, int out_size, void* d_ws, size_t ws_size,
                              hipStream_t stream) {
  const float* query = (const float*)d_in[0];
  const float* key   = (const float*)d_in[1];
  const float* value = (const float*)d_in[2];
  const int*   maskp = (const int*)d_in[3];
  const float* Wq = (const float*)d_in[4];
  const float* bq = (const float*)d_in[5];
  const float* Wk = (const float*)d_in[6];
  const float* bk = (const float*)d_in[7];
  const float* Wv = (const float*)d_in[8];
  const float* bv = (const float*)d_in[9];
  const float* Wo = (const float*)d_in[10];
  const float* bo = (const float*)d_in[11];

  char* ws = (char*)d_ws;
  const size_t SZX = (size_t)S_LEN * D_MODEL * 2;   // 6.29 MB
  const size_t SZW = (size_t)D_MODEL * D_MODEL * 2; // 1.18 MB
  u16* Xq  = (u16*)(ws);
  u16* Xk  = (u16*)(ws + SZX);
  u16* Xv  = (u16*)(ws + 2 * SZX);
  u16* Qb  = (u16*)(ws + 3 * SZX);
  u16* Kb  = (u16*)(ws + 4 * SZX);
  u16* Vtb = (u16*)(ws + 5 * SZX);
  u16* Wqb = (u16*)(ws + 6 * SZX);
  u16* Wkb = (u16*)(ws + 6 * SZX + SZW);
  u16* Wvb = (u16*)(ws + 6 * SZX + 2 * SZW);
  u16* Wob = (u16*)(ws + 6 * SZX + 3 * SZW);
  u16* Ctx = Xq;  // Xq dead after QKV projection; alias. Total ws use ~42.5 MB.

  // fp32 -> bf16 conversions
  CvtArgs ca;
  ca.s[0] = query; ca.s[1] = key; ca.s[2] = value; ca.s[3] = query;
  ca.d[0] = Xq;    ca.d[1] = Xk;  ca.d[2] = Xv;    ca.d[3] = Xq;
  cvt8_kernel<<<dim3(1536, 1, 3), 256, 0, stream>>>(ca, (long)S_LEN * D_MODEL);

  CvtArgs cw;
  cw.s[0] = Wq;  cw.s[1] = Wk;  cw.s[2] = Wv;  cw.s[3] = Wo;
  cw.d[0] = Wqb; cw.d[1] = Wkb; cw.d[2] = Wvb; cw.d[3] = Wob;
  cvt8_kernel<<<dim3(288, 1, 4), 256, 0, stream>>>(cw, (long)D_MODEL * D_MODEL);

  // QKV projections; Q folds 1/sqrt(Dh) * log2(e); V stored transposed for flash PV staging
  ProjArgs pa;
  pa.A[0] = Xq;  pa.A[1] = Xk;  pa.A[2] = Xv;
  pa.W[0] = Wqb; pa.W[1] = Wkb; pa.W[2] = Wvb;
  pa.bias[0] = bq; pa.bias[1] = bk; pa.bias[2] = bv;
  pa.out[0] = Qb; pa.out[1] = Kb; pa.out[2] = Vtb;
  pa.scale[0] = 0.125f * 1.4426950408889634f; pa.scale[1] = 1.f; pa.scale[2] = 1.f;
  pa.mode[0] = 0; pa.mode[1] = 0; pa.mode[2] = 1;
  proj_kernel<<<dim3(32, 6, 3), 256, 0, stream>>>(pa);

  // flash attention -> Ctx (bf16, S x D)
  flash_kernel<<<dim3(64, N_HEADS, 1), 256, 0, stream>>>(Qb, Kb, Vtb, maskp, Ctx);

  // output projection -> fp32 d_out
  ProjArgs po;
  po.A[0] = Ctx; po.A[1] = Ctx; po.A[2] = Ctx;
  po.W[0] = Wob; po.W[1] = Wob; po.W[2] = Wob;
  po.bias[0] = bo; po.bias[1] = bo; po.bias[2] = bo;
  po.out[0] = d_out; po.out[1] = d_out; po.out[2] = d_out;
  po.scale[0] = 1.f; po.scale[1] = 1.f; po.scale[2] = 1.f;
  po.mode[0] = 2; po.mode[1] = 2; po.mode[2] = 2;
  proj_kernel<<<dim3(32, 6, 1), 256, 0, stream>>>(po);
}